// Round 4
// baseline (1587.049 us; speedup 1.0000x reference)
//
#include <hip/hip_runtime.h>
#include <hip/hip_bf16.h>
#include <stdint.h>

#define T_TOK 8192
#define H     1024
#define HF    4096
#define NE    8

typedef __bf16 bf16x8 __attribute__((ext_vector_type(8)));
typedef float  floatx4 __attribute__((ext_vector_type(4)));

typedef const __attribute__((address_space(1))) uint32_t g_u32;
typedef __attribute__((address_space(3))) uint32_t l_u32;

__device__ __forceinline__ void async_ld16(const void* g, void* l) {
  // LDS dest = wave-uniform base + lane*16; per-lane global address
  __builtin_amdgcn_global_load_lds((g_u32*)g, (l_u32*)l, 16, 0, 0);
}

__device__ __forceinline__ unsigned short f2bf(float f) {
  union { float f; uint32_t u; } v; v.f = f;
  uint32_t r = (v.u + 0x7FFFu + ((v.u >> 16) & 1u)) >> 16;
  return (unsigned short)r;
}

// Tiled operand layout ("LDS image"): chunk = 16B of 8 bf16.
// index(shorts) = ((blk*KB + kblk)*512 + q*128 + row)*8 + elem
//   blk  = row_block (m/128 or n/128), kblk = k/32, q = (k>>3)&3, elem = k&7.
// Staging a (128-row x 32-k) tile = 8 KB contiguous -> 8 identity DMA instrs.
// LDS chunk order [q][row]: ds_read fragment (row=l15, q=lane>>4) -> consecutive
// lanes read consecutive chunks -> distinct bank-quads -> conflict-free (R1=0 evidence).

// ---------------- init: zero counts ----------------
__global__ void k_init(int* counts) {
  if (threadIdx.x < NE) counts[threadIdx.x] = 0;
}

// ---------------- router: one wave per token ----------------
__global__ __launch_bounds__(256) void k_router(const float* __restrict__ x,
                                                const float* __restrict__ gw,
                                                int* counts, int* topk_e, float* topk_w) {
  int wave = threadIdx.x >> 6, lane = threadIdx.x & 63;
  int t = blockIdx.x * 4 + wave;
  float acc[NE];
#pragma unroll
  for (int e = 0; e < NE; e++) acc[e] = 0.f;
  const float* xr = x + (size_t)t * H;
  for (int k = lane; k < H; k += 64) {
    float xv = xr[k];
    const float* g = gw + (size_t)k * NE;
#pragma unroll
    for (int e = 0; e < NE; e++) acc[e] += xv * g[e];
  }
#pragma unroll
  for (int off = 32; off > 0; off >>= 1) {
#pragma unroll
    for (int e = 0; e < NE; e++) acc[e] += __shfl_xor(acc[e], off, 64);
  }
  if (lane == 0) {
    int e1 = 0;
#pragma unroll
    for (int e = 1; e < NE; e++) if (acc[e] > acc[e1]) e1 = e;
    int e2 = (e1 == 0) ? 1 : 0;
#pragma unroll
    for (int e = 0; e < NE; e++) if (e != e1 && acc[e] > acc[e2]) e2 = e;
    float w1 = 1.f / (1.f + expf(acc[e2] - acc[e1]));
    topk_e[2 * t] = e1; topk_e[2 * t + 1] = e2;
    topk_w[2 * t] = w1; topk_w[2 * t + 1] = 1.f - w1;
    atomicAdd(&counts[e1], 1);
    atomicAdd(&counts[e2], 1);
  }
}

// ---------------- scan: 128-padded offsets + zero cursors ----------------
__global__ void k_scan(const int* counts, int* offsets, int* cursors) {
  if (threadIdx.x == 0) {
    int s = 0;
    for (int e = 0; e < NE; e++) {
      offsets[e] = s;
      s += (counts[e] + 127) & ~127;   // pad each segment to 128 rows
      cursors[e] = 0;
    }
    offsets[NE] = s;
  }
}

// ---------------- fill: slot assignment + gather x -> tiled bf16 A (KB=32) ------
__global__ __launch_bounds__(256) void k_fill(const float* __restrict__ x,
                                              const int* __restrict__ topk_e,
                                              const float* __restrict__ topk_w,
                                              const int* __restrict__ offsets, int* cursors,
                                              int* tok_slot, float* row_weight,
                                              unsigned short* __restrict__ A_pack) {
  int wave = threadIdx.x >> 6, lane = threadIdx.x & 63;
  int t = blockIdx.x * 4 + wave;
  int s1 = 0, s2 = 0;
  if (lane == 0) {
    int e1 = topk_e[2 * t], e2 = topk_e[2 * t + 1];
    s1 = offsets[e1] + atomicAdd(&cursors[e1], 1);
    s2 = offsets[e2] + atomicAdd(&cursors[e2], 1);
    tok_slot[2 * t] = s1; tok_slot[2 * t + 1] = s2;
    row_weight[s1] = topk_w[2 * t];
    row_weight[s2] = topk_w[2 * t + 1];
  }
  s1 = __shfl(s1, 0, 64);
  s2 = __shfl(s2, 0, 64);
  const float* xr = x + (size_t)t * H;
  size_t mb1 = (size_t)(s1 >> 7) * 32, r1 = s1 & 127;
  size_t mb2 = (size_t)(s2 >> 7) * 32, r2 = s2 & 127;
#pragma unroll
  for (int d = 0; d < 2; d++) {
    int kc = lane * 2 + d;             // chunk-col 0..127
    int kblk = kc >> 2, q = kc & 3;
    float4 v0 = *(const float4*)(xr + kc * 8);
    float4 v1 = *(const float4*)(xr + kc * 8 + 4);
    ushort4 a, b;
    a.x = f2bf(v0.x); a.y = f2bf(v0.y); a.z = f2bf(v0.z); a.w = f2bf(v0.w);
    b.x = f2bf(v1.x); b.y = f2bf(v1.y); b.z = f2bf(v1.z); b.w = f2bf(v1.w);
    size_t c1 = ((mb1 + kblk) * 512 + (size_t)q * 128 + r1) * 8;
    size_t c2 = ((mb2 + kblk) * 512 + (size_t)q * 128 + r2) * 8;
    *(ushort4*)(A_pack + c1) = a; *(ushort4*)(A_pack + c1 + 4) = b;
    *(ushort4*)(A_pack + c2) = a; *(ushort4*)(A_pack + c2 + 4) = b;
  }
}

// ---------------- transpose + cvt: [E][K][N] f32 -> tiled bf16 [E][nb][kblk][q][row] ----
__global__ __launch_bounds__(256) void k_transpose_cvt(const float* __restrict__ src,
                                                       unsigned short* __restrict__ dst,
                                                       int K, int N) {
  __shared__ unsigned short tile[64][65];
  int e = blockIdx.z;
  int KB = K >> 5, NB = N >> 7;
  int k0 = blockIdx.x * 64, n0 = blockIdx.y * 64;
  const float* S = src + (size_t)e * K * N;
  int tr = threadIdx.x >> 4;
  int tc = (threadIdx.x & 15) * 4;
#pragma unroll
  for (int rr = 0; rr < 64; rr += 16) {
    float4 v = *(const float4*)(S + (size_t)(k0 + tr + rr) * N + n0 + tc);
    tile[tr + rr][tc + 0] = f2bf(v.x);
    tile[tr + rr][tc + 1] = f2bf(v.y);
    tile[tr + rr][tc + 2] = f2bf(v.z);
    tile[tr + rr][tc + 3] = f2bf(v.w);
  }
  __syncthreads();
#pragma unroll
  for (int rr = 0; rr < 64; rr += 16) {
    int i = tr + rr;
    int n = n0 + i, k = k0 + tc;
    ushort4 o;
    o.x = tile[tc + 0][i]; o.y = tile[tc + 1][i];
    o.z = tile[tc + 2][i]; o.w = tile[tc + 3][i];
    size_t idx = ((((size_t)e * NB + (n >> 7)) * KB + (k >> 5)) * 512 +
                  (size_t)((k >> 3) & 3) * 128 + (n & 127)) * 8 + (tc & 7);
    *(ushort4*)(dst + idx) = o;
  }
}

// ---------------- GEMM: 128x128 tile, BK=32, 4 waves, mfma_f32_16x16x32_bf16 ----
// Operands pre-tiled; staging = identity copy (8 x 1KB contiguous DMA per operand).
// grid: x = m-tile (fastest, shares B across co-resident blocks), y = n-tile, z = expert.
template <int KB, bool SECOND>
__global__ __launch_bounds__(256) void k_gemm(const unsigned short* __restrict__ A,
                                              const unsigned short* __restrict__ BT,
                                              const int* __restrict__ counts,
                                              const int* __restrict__ offsets,
                                              const float* __restrict__ row_weight,
                                              unsigned short* __restrict__ hidden,
                                              float* __restrict__ out_slot, int NB) {
  int e = blockIdx.z;
  int cnt = counts[e];
  int mt = blockIdx.x;
  if (mt * 128 >= cnt) return;
  int nb = blockIdx.y;
  int moff = offsets[e];                 // multiple of 128
  int mb = (moff >> 7) + mt;

  __shared__ __align__(16) unsigned short As[4096];
  __shared__ __align__(16) unsigned short Bs[4096];

  int tid = threadIdx.x, wave = tid >> 6, lane = tid & 63;
  int wm = wave & 1, wn = wave >> 1;

  floatx4 acc[4][4] = {};

  const unsigned short* Ablk = A + (size_t)mb * KB * 4096;
  const unsigned short* Bblk = BT + ((size_t)e * NB + nb) * KB * 4096;

  for (int kblk = 0; kblk < KB; kblk++) {
    __syncthreads();
#pragma unroll
    for (int s = 0; s < 2; s++) {
      int g = s * 4 + wave;
      size_t off = (size_t)kblk * 4096 + g * 512 + lane * 8;
      async_ld16(Ablk + off, (void*)(As + g * 512));
      async_ld16(Bblk + off, (void*)(Bs + g * 512));
    }
    __syncthreads();

    int q = lane >> 4, l15 = lane & 15;
    bf16x8 aF[4], bF[4];
#pragma unroll
    for (int i = 0; i < 4; i++)
      aF[i] = *(const bf16x8*)&As[((size_t)q * 128 + wm * 64 + i * 16 + l15) * 8];
#pragma unroll
    for (int j = 0; j < 4; j++)
      bF[j] = *(const bf16x8*)&Bs[((size_t)q * 128 + wn * 64 + j * 16 + l15) * 8];
#pragma unroll
    for (int i = 0; i < 4; i++)
#pragma unroll
      for (int j = 0; j < 4; j++)
        acc[i][j] = __builtin_amdgcn_mfma_f32_16x16x32_bf16(aF[i], bF[j], acc[i][j], 0, 0, 0);
  }

  int q = lane >> 4, l15 = lane & 15;
#pragma unroll
  for (int i = 0; i < 4; i++) {
#pragma unroll
    for (int r = 0; r < 4; r++) {
      int rl = wm * 64 + i * 16 + q * 4 + r;
      int grow = mt * 128 + rl;
      if (grow < cnt) {
        int p = moff + grow;
        if (!SECOND) {
          float w = row_weight[p];
#pragma unroll
          for (int j = 0; j < 4; j++) {
            int col = nb * 128 + wn * 64 + j * 16 + l15;
            float v = acc[i][j][r];
            v = (v > 0.f) ? v * v * w : 0.f;
            // hidden in GEMM2-A tiled layout (KB2 = 128)
            size_t idx = (((size_t)(p >> 7) * 128 + (col >> 5)) * 512 +
                          (size_t)((col >> 3) & 3) * 128 + (p & 127)) * 8 + (col & 7);
            hidden[idx] = f2bf(v);
          }
        } else {
#pragma unroll
          for (int j = 0; j < 4; j++) {
            int col = nb * 128 + wn * 64 + j * 16 + l15;
            out_slot[(size_t)p * H + col] = acc[i][j][r];
          }
        }
      }
    }
  }
}

// ---------------- combine: out[t] = out_slot[s1] + out_slot[s2] ----------------
__global__ __launch_bounds__(256) void k_combine(const float* __restrict__ out_slot,
                                                 const int* __restrict__ tok_slot,
                                                 float* __restrict__ out) {
  int t = blockIdx.x;
  int s1 = tok_slot[2 * t], s2 = tok_slot[2 * t + 1];
  int c = threadIdx.x * 4;
  float4 a = *(const float4*)(out_slot + (size_t)s1 * H + c);
  float4 b = *(const float4*)(out_slot + (size_t)s2 * H + c);
  float4 o;
  o.x = a.x + b.x; o.y = a.y + b.y; o.z = a.z + b.z; o.w = a.w + b.w;
  *(float4*)(out + (size_t)t * H + c) = o;
}

extern "C" void kernel_launch(void* const* d_in, const int* in_sizes, int n_in,
                              void* d_out, int out_size, void* d_ws, size_t ws_size,
                              hipStream_t stream) {
  const float* x  = (const float*)d_in[0];   // [8192,1024]
  const float* gw = (const float*)d_in[1];   // [1024,8]
  const float* w1 = (const float*)d_in[2];   // [8,1024,4096]
  const float* w2 = (const float*)d_in[3];   // [8,4096,1024]
  float* out = (float*)d_out;

  uint8_t* W = (uint8_t*)d_ws;
  size_t KB_ = 1024, MB_ = 1ull << 20;
  int*   counts    = (int*)(W + 0);
  int*   cursors   = (int*)(W + 256);
  int*   offsets   = (int*)(W + 512);
  int*   topk_e    = (int*)(W + 64 * KB_);
  float* topk_w    = (float*)(W + 192 * KB_);
  int*   tok_slot  = (int*)(W + 320 * KB_);
  float* row_weight= (float*)(W + 448 * KB_);   // padded slots <= 17400 -> 70KB, has 128KB
  // tiled big buffers
  unsigned short* A_pack = (unsigned short*)(W + 1 * MB_);    // 137 mb * 256KB = 34.3MB
  unsigned short* wt1    = (unsigned short*)(W + 36 * MB_);   // 64MB
  unsigned short* wt2    = (unsigned short*)(W + 100 * MB_);  // 64MB
  unsigned short* hidden = (unsigned short*)(W + 164 * MB_);  // 137 mb * 1MB = 137MB -> 301MB
  float* out_slot = (float*)(W + 1 * MB_);  // aliases A_pack+wt1 (dead after GEMM1): needs ~70MB < 99MB

  k_init<<<1, 64, 0, stream>>>(counts);
  k_router<<<T_TOK / 4, 256, 0, stream>>>(x, gw, counts, topk_e, topk_w);
  k_scan<<<1, 64, 0, stream>>>(counts, offsets, cursors);
  k_fill<<<T_TOK / 4, 256, 0, stream>>>(x, topk_e, topk_w, offsets, cursors,
                                        tok_slot, row_weight, A_pack);
  // w1: K=1024, N=4096 ; w2: K=4096, N=1024  (both -> tiled bf16)
  k_transpose_cvt<<<dim3(H / 64, HF / 64, NE), 256, 0, stream>>>(w1, wt1, H, HF);
  k_transpose_cvt<<<dim3(HF / 64, H / 64, NE), 256, 0, stream>>>(w2, wt2, HF, H);

  // GEMM1: [cnt_e,1024] @ w1 -> relu^2*w -> hidden (bf16, tiled for GEMM2)
  k_gemm<32, false><<<dim3(T_TOK / 128, HF / 128, NE), 256, 0, stream>>>(
      A_pack, wt1, counts, offsets, row_weight, hidden, out_slot, HF / 128);
  // GEMM2: [cnt_e,4096] @ w2 -> out_slot (fp32)
  k_gemm<128, true><<<dim3(T_TOK / 128, H / 128, NE), 256, 0, stream>>>(
      hidden, wt2, counts, offsets, row_weight, hidden, out_slot, H / 128);
  // combine the two expert contributions per token
  k_combine<<<T_TOK, 256, 0, stream>>>(out_slot, tok_slot, out);
}

// Round 5
// 1310.299 us; speedup vs baseline: 1.2112x; 1.2112x over previous
//
#include <hip/hip_runtime.h>
#include <hip/hip_bf16.h>
#include <stdint.h>

#define T_TOK 8192
#define H     1024
#define HF    4096
#define NE    8

typedef __bf16 bf16x8 __attribute__((ext_vector_type(8)));
typedef float  floatx4 __attribute__((ext_vector_type(4)));

typedef const __attribute__((address_space(1))) uint32_t g_u32;
typedef __attribute__((address_space(3))) uint32_t l_u32;

__device__ __forceinline__ void async_ld16(const void* g, void* l) {
  // LDS dest = wave-uniform base + lane*16; per-lane global address
  __builtin_amdgcn_global_load_lds((g_u32*)g, (l_u32*)l, 16, 0, 0);
}

__device__ __forceinline__ unsigned short f2bf(float f) {
  union { float f; uint32_t u; } v; v.f = f;
  uint32_t r = (v.u + 0x7FFFu + ((v.u >> 16) & 1u)) >> 16;
  return (unsigned short)r;
}

// Tiled operand layout ("LDS image"): chunk = 16B of 8 bf16.
// index(shorts) = ((blk*KB + kblk)*512 + q*128 + row)*8 + elem
//   blk = row_block (m/128 or n/128), kblk = k/32, q = (k>>3)&3, elem = k&7.
// Staging a (128-row x 32-k) tile = 8KB contiguous -> identity DMA (R4: conflicts=0).
// Grid MUST be n-tile-fastest so co-resident blocks share the A m-block:
// A staging then hits L2 (~200cyc) instead of HBM (~900cyc) on the barrier
// critical path (R3=336us shared vs R4=500us private, latency-bound evidence).

// ---------------- init: zero counts ----------------
__global__ void k_init(int* counts) {
  if (threadIdx.x < NE) counts[threadIdx.x] = 0;
}

// ---------------- router: one wave per token ----------------
__global__ __launch_bounds__(256) void k_router(const float* __restrict__ x,
                                                const float* __restrict__ gw,
                                                int* counts, int* topk_e, float* topk_w) {
  int wave = threadIdx.x >> 6, lane = threadIdx.x & 63;
  int t = blockIdx.x * 4 + wave;
  float acc[NE];
#pragma unroll
  for (int e = 0; e < NE; e++) acc[e] = 0.f;
  const float* xr = x + (size_t)t * H;
  for (int k = lane; k < H; k += 64) {
    float xv = xr[k];
    const float* g = gw + (size_t)k * NE;
#pragma unroll
    for (int e = 0; e < NE; e++) acc[e] += xv * g[e];
  }
#pragma unroll
  for (int off = 32; off > 0; off >>= 1) {
#pragma unroll
    for (int e = 0; e < NE; e++) acc[e] += __shfl_xor(acc[e], off, 64);
  }
  if (lane == 0) {
    int e1 = 0;
#pragma unroll
    for (int e = 1; e < NE; e++) if (acc[e] > acc[e1]) e1 = e;
    int e2 = (e1 == 0) ? 1 : 0;
#pragma unroll
    for (int e = 0; e < NE; e++) if (e != e1 && acc[e] > acc[e2]) e2 = e;
    float w1 = 1.f / (1.f + expf(acc[e2] - acc[e1]));
    topk_e[2 * t] = e1; topk_e[2 * t + 1] = e2;
    topk_w[2 * t] = w1; topk_w[2 * t + 1] = 1.f - w1;
    atomicAdd(&counts[e1], 1);
    atomicAdd(&counts[e2], 1);
  }
}

// ---------------- scan: 128-padded offsets + zero cursors ----------------
__global__ void k_scan(const int* counts, int* offsets, int* cursors) {
  if (threadIdx.x == 0) {
    int s = 0;
    for (int e = 0; e < NE; e++) {
      offsets[e] = s;
      s += (counts[e] + 127) & ~127;   // pad each segment to 128 rows
      cursors[e] = 0;
    }
    offsets[NE] = s;
  }
}

// ---------------- fill: slot assignment + gather x -> tiled bf16 A (KB=32) ------
__global__ __launch_bounds__(256) void k_fill(const float* __restrict__ x,
                                              const int* __restrict__ topk_e,
                                              const float* __restrict__ topk_w,
                                              const int* __restrict__ offsets, int* cursors,
                                              int* tok_slot, float* row_weight,
                                              unsigned short* __restrict__ A_pack) {
  int wave = threadIdx.x >> 6, lane = threadIdx.x & 63;
  int t = blockIdx.x * 4 + wave;
  int s1 = 0, s2 = 0;
  if (lane == 0) {
    int e1 = topk_e[2 * t], e2 = topk_e[2 * t + 1];
    s1 = offsets[e1] + atomicAdd(&cursors[e1], 1);
    s2 = offsets[e2] + atomicAdd(&cursors[e2], 1);
    tok_slot[2 * t] = s1; tok_slot[2 * t + 1] = s2;
    row_weight[s1] = topk_w[2 * t];
    row_weight[s2] = topk_w[2 * t + 1];
  }
  s1 = __shfl(s1, 0, 64);
  s2 = __shfl(s2, 0, 64);
  const float* xr = x + (size_t)t * H;
  size_t mb1 = (size_t)(s1 >> 7) * 32, r1 = s1 & 127;
  size_t mb2 = (size_t)(s2 >> 7) * 32, r2 = s2 & 127;
#pragma unroll
  for (int d = 0; d < 2; d++) {
    int kc = lane * 2 + d;             // chunk-col 0..127
    int kblk = kc >> 2, q = kc & 3;
    float4 v0 = *(const float4*)(xr + kc * 8);
    float4 v1 = *(const float4*)(xr + kc * 8 + 4);
    ushort4 a, b;
    a.x = f2bf(v0.x); a.y = f2bf(v0.y); a.z = f2bf(v0.z); a.w = f2bf(v0.w);
    b.x = f2bf(v1.x); b.y = f2bf(v1.y); b.z = f2bf(v1.z); b.w = f2bf(v1.w);
    size_t c1 = ((mb1 + kblk) * 512 + (size_t)q * 128 + r1) * 8;
    size_t c2 = ((mb2 + kblk) * 512 + (size_t)q * 128 + r2) * 8;
    *(ushort4*)(A_pack + c1) = a; *(ushort4*)(A_pack + c1 + 4) = b;
    *(ushort4*)(A_pack + c2) = a; *(ushort4*)(A_pack + c2 + 4) = b;
  }
}

// ---- transpose + cvt: [E][K][N] f32 -> tiled bf16, register 4x4 micro-transpose ----
// Thread (kq = tid>>4, nr = tid&15) handles k in [k0+kq*4, +4) x n in [n0+nr*4, +4).
// Reads: 4 float4, lane-consecutive along n -> 256B-contiguous groups.
// Writes: 4 ushort4 (k-quad per fixed n); c-loop + kq pairs fully cover 64B lines.
__global__ __launch_bounds__(256) void k_transpose_cvt(const float* __restrict__ src,
                                                       unsigned short* __restrict__ dst,
                                                       int K, int N) {
  int e = blockIdx.z;
  int KB = K >> 5, NB = N >> 7;
  int k0 = blockIdx.x * 64, n0 = blockIdx.y * 64;
  const float* S = src + (size_t)e * K * N;
  unsigned short* De = dst + (size_t)e * NB * KB * 4096;
  int kq = threadIdx.x >> 4, nr = threadIdx.x & 15;
  int kb = k0 + kq * 4;
  const float* p = S + (size_t)kb * N + n0 + nr * 4;
  float4 r0 = *(const float4*)(p);
  float4 r1 = *(const float4*)(p + N);
  float4 r2 = *(const float4*)(p + 2 * N);
  float4 r3 = *(const float4*)(p + 3 * N);
  float cols[4][4] = {{r0.x, r1.x, r2.x, r3.x}, {r0.y, r1.y, r2.y, r3.y},
                      {r0.z, r1.z, r2.z, r3.z}, {r0.w, r1.w, r2.w, r3.w}};
  int kblk = kb >> 5, q = (kb >> 3) & 3, el = kb & 7;  // el in {0,4}
#pragma unroll
  for (int c = 0; c < 4; c++) {
    int n = n0 + nr * 4 + c;
    size_t idx = (((size_t)(n >> 7) * KB + kblk) * 512 + (size_t)q * 128 + (n & 127)) * 8 + el;
    ushort4 o;
    o.x = f2bf(cols[c][0]); o.y = f2bf(cols[c][1]);
    o.z = f2bf(cols[c][2]); o.w = f2bf(cols[c][3]);
    *(ushort4*)(De + idx) = o;
  }
}

// ---------------- GEMM: 128x128 tile, BK=32, 4 waves, mfma_f32_16x16x32_bf16 ----
// Operands pre-tiled; staging = identity copy (8 x 1KB contiguous DMA per operand).
// grid: x = n-tile (fastest -> co-resident blocks share A m-block), y = m-tile, z = expert.
template <int KB, bool SECOND>
__global__ __launch_bounds__(256) void k_gemm(const unsigned short* __restrict__ A,
                                              const unsigned short* __restrict__ BT,
                                              const int* __restrict__ counts,
                                              const int* __restrict__ offsets,
                                              const float* __restrict__ row_weight,
                                              unsigned short* __restrict__ hidden,
                                              float* __restrict__ out_slot, int NB) {
  int e = blockIdx.z;
  int cnt = counts[e];
  int mt = blockIdx.y;
  if (mt * 128 >= cnt) return;
  int nb = blockIdx.x;
  int moff = offsets[e];                 // multiple of 128
  int mb = (moff >> 7) + mt;

  __shared__ __align__(16) unsigned short As[4096];
  __shared__ __align__(16) unsigned short Bs[4096];

  int tid = threadIdx.x, wave = tid >> 6, lane = tid & 63;
  int wm = wave & 1, wn = wave >> 1;

  floatx4 acc[4][4] = {};

  const unsigned short* Ablk = A + (size_t)mb * KB * 4096;
  const unsigned short* Bblk = BT + ((size_t)e * NB + nb) * KB * 4096;

  for (int kblk = 0; kblk < KB; kblk++) {
    __syncthreads();
#pragma unroll
    for (int s = 0; s < 2; s++) {
      int g = s * 4 + wave;
      size_t off = (size_t)kblk * 4096 + g * 512 + lane * 8;
      async_ld16(Ablk + off, (void*)(As + g * 512));
      async_ld16(Bblk + off, (void*)(Bs + g * 512));
    }
    __syncthreads();

    int q = lane >> 4, l15 = lane & 15;
    bf16x8 aF[4], bF[4];
#pragma unroll
    for (int i = 0; i < 4; i++)
      aF[i] = *(const bf16x8*)&As[((size_t)q * 128 + wm * 64 + i * 16 + l15) * 8];
#pragma unroll
    for (int j = 0; j < 4; j++)
      bF[j] = *(const bf16x8*)&Bs[((size_t)q * 128 + wn * 64 + j * 16 + l15) * 8];
#pragma unroll
    for (int i = 0; i < 4; i++)
#pragma unroll
      for (int j = 0; j < 4; j++)
        acc[i][j] = __builtin_amdgcn_mfma_f32_16x16x32_bf16(aF[i], bF[j], acc[i][j], 0, 0, 0);
  }

  int q = lane >> 4, l15 = lane & 15;
#pragma unroll
  for (int i = 0; i < 4; i++) {
#pragma unroll
    for (int r = 0; r < 4; r++) {
      int rl = wm * 64 + i * 16 + q * 4 + r;
      int grow = mt * 128 + rl;
      if (grow < cnt) {
        int p = moff + grow;
        if (!SECOND) {
          float w = row_weight[p];
#pragma unroll
          for (int j = 0; j < 4; j++) {
            int col = nb * 128 + wn * 64 + j * 16 + l15;
            float v = acc[i][j][r];
            v = (v > 0.f) ? v * v * w : 0.f;
            // hidden in GEMM2-A tiled layout (KB2 = 128)
            size_t idx = (((size_t)(p >> 7) * 128 + (col >> 5)) * 512 +
                          (size_t)((col >> 3) & 3) * 128 + (p & 127)) * 8 + (col & 7);
            hidden[idx] = f2bf(v);
          }
        } else {
#pragma unroll
          for (int j = 0; j < 4; j++) {
            int col = nb * 128 + wn * 64 + j * 16 + l15;
            out_slot[(size_t)p * H + col] = acc[i][j][r];
          }
        }
      }
    }
  }
}

// ---------------- combine: out[t] = out_slot[s1] + out_slot[s2] ----------------
__global__ __launch_bounds__(256) void k_combine(const float* __restrict__ out_slot,
                                                 const int* __restrict__ tok_slot,
                                                 float* __restrict__ out) {
  int t = blockIdx.x;
  int s1 = tok_slot[2 * t], s2 = tok_slot[2 * t + 1];
  int c = threadIdx.x * 4;
  float4 a = *(const float4*)(out_slot + (size_t)s1 * H + c);
  float4 b = *(const float4*)(out_slot + (size_t)s2 * H + c);
  float4 o;
  o.x = a.x + b.x; o.y = a.y + b.y; o.z = a.z + b.z; o.w = a.w + b.w;
  *(float4*)(out + (size_t)t * H + c) = o;
}

extern "C" void kernel_launch(void* const* d_in, const int* in_sizes, int n_in,
                              void* d_out, int out_size, void* d_ws, size_t ws_size,
                              hipStream_t stream) {
  const float* x  = (const float*)d_in[0];   // [8192,1024]
  const float* gw = (const float*)d_in[1];   // [1024,8]
  const float* w1 = (const float*)d_in[2];   // [8,1024,4096]
  const float* w2 = (const float*)d_in[3];   // [8,4096,1024]
  float* out = (float*)d_out;

  uint8_t* W = (uint8_t*)d_ws;
  size_t KB_ = 1024, MB_ = 1ull << 20;
  int*   counts    = (int*)(W + 0);
  int*   cursors   = (int*)(W + 256);
  int*   offsets   = (int*)(W + 512);
  int*   topk_e    = (int*)(W + 64 * KB_);
  float* topk_w    = (float*)(W + 192 * KB_);
  int*   tok_slot  = (int*)(W + 320 * KB_);
  float* row_weight= (float*)(W + 448 * KB_);
  // tiled big buffers
  unsigned short* A_pack = (unsigned short*)(W + 1 * MB_);    // ~34.3MB
  unsigned short* wt1    = (unsigned short*)(W + 36 * MB_);   // 64MB
  unsigned short* wt2    = (unsigned short*)(W + 100 * MB_);  // 64MB
  unsigned short* hidden = (unsigned short*)(W + 164 * MB_);  // ~137MB -> 301MB total
  float* out_slot = (float*)(W + 1 * MB_);  // aliases A_pack+wt1 (dead after GEMM1), ~71MB < 99MB

  k_init<<<1, 64, 0, stream>>>(counts);
  k_router<<<T_TOK / 4, 256, 0, stream>>>(x, gw, counts, topk_e, topk_w);
  k_scan<<<1, 64, 0, stream>>>(counts, offsets, cursors);
  k_fill<<<T_TOK / 4, 256, 0, stream>>>(x, topk_e, topk_w, offsets, cursors,
                                        tok_slot, row_weight, A_pack);
  // w1: K=1024, N=4096 ; w2: K=4096, N=1024  (both -> tiled bf16)
  k_transpose_cvt<<<dim3(H / 64, HF / 64, NE), 256, 0, stream>>>(w1, wt1, H, HF);
  k_transpose_cvt<<<dim3(HF / 64, H / 64, NE), 256, 0, stream>>>(w2, wt2, HF, H);

  // GEMM1: [cnt_e,1024] @ w1 -> relu^2*w -> hidden (bf16, tiled for GEMM2)
  k_gemm<32, false><<<dim3(HF / 128, T_TOK / 128, NE), 256, 0, stream>>>(
      A_pack, wt1, counts, offsets, row_weight, hidden, out_slot, HF / 128);
  // GEMM2: [cnt_e,4096] @ w2 -> out_slot (fp32)
  k_gemm<128, true><<<dim3(H / 128, T_TOK / 128, NE), 256, 0, stream>>>(
      hidden, wt2, counts, offsets, row_weight, hidden, out_slot, H / 128);
  // combine the two expert contributions per token
  k_combine<<<T_TOK, 256, 0, stream>>>(out_slot, tok_slot, out);
}